// Round 2
// baseline (268.779 us; speedup 1.0000x reference)
//
#include <hip/hip_runtime.h>
#include <hip/hip_fp16.h>

constexpr int N_NODES = 50000;
constexpr int N_EDGES = 640000;

constexpr int NBLK  = 256;                    // edge-chunk blocks
constexpr int EPB   = N_EDGES / NBLK;         // 2500 (exact)
constexpr int NBUCK = (N_NODES + 255) / 256;  // 196 buckets of 256 dst each
constexpr int GBM   = (N_NODES + 63) / 64;    // mfma-gemm blocks (64 rows each)

typedef _Float16 half8  __attribute__((ext_vector_type(8)));
typedef _Float16 half4v __attribute__((ext_vector_type(4)));
typedef float    floatx4 __attribute__((ext_vector_type(4)));

// ---------------- W -> W^T fp16 conversion (one-time, tiny) + deg zero ----------------

__global__ void wconv_k(const float* __restrict__ W1, const float* __restrict__ W2,
                        const float* __restrict__ W3, _Float16* __restrict__ Wt1,
                        _Float16* __restrict__ Wt2, _Float16* __restrict__ Wt3,
                        float* __restrict__ deg) {
    int i = blockIdx.x * 256 + threadIdx.x;
    if (i < N_NODES) deg[i] = 0.f;
    if (i < 16384) {
        int n = i >> 7, k = i & 127;
        Wt1[n * 128 + k] = (_Float16)W1[k * 128 + n];
    } else if (i < 32768) {
        int j = i - 16384; int n = j >> 7, k = j & 127;
        Wt2[n * 128 + k] = (_Float16)W2[k * 128 + n];
    } else if (i < 32768 + 6144) {
        int j = i - 32768; int n = j >> 7, k = j & 127;
        Wt3[n * 128 + k] = (_Float16)((n < 40) ? W3[k * 40 + n] : 0.f);
    }
}

// ---------------- MFMA GEMM: H[N,F_OUT] = X[N,128] @ W, fp16 in/out, fp32 acc ----------------
// 64 rows/block, 4 waves, each wave 16 rows x F_OUT cols via 16x16x32 f16 MFMA.
// A from LDS (pad-136 rows, ds_read_b128); B from global Wt[n][k] (L1-resident).
// FUSE_HIST: blocks [0,NBLK) do the LDS bucket histogram + global deg atomics instead.

template<typename TIN, int F_OUT, int NT, bool FUSE_HIST>
__global__ __launch_bounds__(256) void gemm_mfma_k(const TIN* __restrict__ X,
        const _Float16* __restrict__ Wt, __half* __restrict__ H,
        const int* __restrict__ dst, int* __restrict__ gh,
        const float* __restrict__ ew, float* __restrict__ deg) {
    if constexpr (FUSE_HIST) {
        if (blockIdx.x < NBLK) {
            __shared__ int lh[256];
            int t = threadIdx.x, b = blockIdx.x;
            lh[t] = 0;
            __syncthreads();
            int e0 = b * EPB;
            for (int j = t; j < EPB; j += 256) {
                int d = dst[e0 + j];
                atomicAdd(&lh[d >> 8], 1);
                atomicAdd(&deg[d], ew[e0 + j]);
            }
            __syncthreads();
            if (t < NBUCK) gh[b * NBUCK + t] = lh[t];
            return;
        }
    }
    int bid = FUSE_HIST ? (int)blockIdx.x - NBLK : (int)blockIdx.x;

    __shared__ _Float16 Xs[64 * 136];      // 64 rows, stride 136 (16B-aligned pad)
    int tid = threadIdx.x;
    int row0 = bid * 64;

    if constexpr (sizeof(TIN) == 4) {      // fp32 input -> convert
        for (int idx = tid; idx < 2048; idx += 256) {
            int r = idx >> 5, c4 = idx & 31;
            float4 v = {0.f, 0.f, 0.f, 0.f};
            if (row0 + r < N_NODES)
                v = *(const float4*)((const float*)X + (size_t)(row0 + r) * 128 + c4 * 4);
            half4v h;
            h[0] = (_Float16)v.x; h[1] = (_Float16)v.y;
            h[2] = (_Float16)v.z; h[3] = (_Float16)v.w;
            *(half4v*)&Xs[r * 136 + c4 * 4] = h;
        }
    } else {                               // fp16 input -> raw copy
        for (int idx = tid; idx < 1024; idx += 256) {
            int r = idx >> 4, c8 = idx & 15;
            int4 v = {0, 0, 0, 0};
            if (row0 + r < N_NODES)
                v = *(const int4*)((const __half*)X + (size_t)(row0 + r) * 128 + c8 * 8);
            *(int4*)&Xs[r * 136 + c8 * 8] = v;
        }
    }
    __syncthreads();

    int lane = tid & 63;
    int wv   = tid >> 6;                   // wave 0..3 -> rows wv*16..+15
    int m    = lane & 15;
    int q    = lane >> 4;

    half8 af[4];
    #pragma unroll
    for (int kt = 0; kt < 4; kt++)
        af[kt] = *(const half8*)&Xs[(wv * 16 + m) * 136 + kt * 32 + q * 8];

    floatx4 acc[NT];
    #pragma unroll
    for (int nt = 0; nt < NT; nt++) { acc[nt][0] = 0.f; acc[nt][1] = 0.f; acc[nt][2] = 0.f; acc[nt][3] = 0.f; }

    #pragma unroll
    for (int nt = 0; nt < NT; nt++) {
        const _Float16* wp = Wt + (size_t)(nt * 16 + m) * 128 + q * 8;
        half8 b0 = *(const half8*)(wp);
        half8 b1 = *(const half8*)(wp + 32);
        half8 b2 = *(const half8*)(wp + 64);
        half8 b3 = *(const half8*)(wp + 96);
        acc[nt] = __builtin_amdgcn_mfma_f32_16x16x32_f16(af[0], b0, acc[nt], 0, 0, 0);
        acc[nt] = __builtin_amdgcn_mfma_f32_16x16x32_f16(af[1], b1, acc[nt], 0, 0, 0);
        acc[nt] = __builtin_amdgcn_mfma_f32_16x16x32_f16(af[2], b2, acc[nt], 0, 0, 0);
        acc[nt] = __builtin_amdgcn_mfma_f32_16x16x32_f16(af[3], b3, acc[nt], 0, 0, 0);
    }

    // C -> own wave's LDS region (rows wv*16..+15 only; no cross-wave hazard)
    #pragma unroll
    for (int nt = 0; nt < NT; nt++) {
        #pragma unroll
        for (int r = 0; r < 4; r++)
            Xs[(wv * 16 + q * 4 + r) * 136 + nt * 16 + m] = (_Float16)acc[nt][r];
    }

    // coalesced copy-out of own region
    if constexpr (F_OUT == 128) {
        for (int g = lane; g < 256; g += 64) {
            int r = g >> 4, c8 = g & 15;
            int row = row0 + wv * 16 + r;
            if (row < N_NODES)
                *(int4*)((__half*)H + (size_t)row * 128 + c8 * 8) =
                    *(const int4*)&Xs[(wv * 16 + r) * 136 + c8 * 8];
        }
    } else {                               // F_OUT = 40: 5 int4 per row
        for (int g = lane; g < 80; g += 64) {
            int r = g / 5, seg = g - r * 5;
            int row = row0 + wv * 16 + r;
            if (row < N_NODES)
                *(int4*)((__half*)H + (size_t)row * 40 + seg * 8) =
                    *(const int4*)&Xs[(wv * 16 + r) * 136 + seg * 8];
        }
    }
}

// ---------------- scan1: per-bucket exclusive prefix over edge-chunks + dinv ----------------
// grid = NBUCK blocks x 256 threads: thread t of block b also computes dinv[b*256+t]
// (deg is complete: produced by the hist blocks of the previous dispatch).

__global__ __launch_bounds__(256) void scan1_k(int* __restrict__ gh, int* __restrict__ total,
                                               const float* __restrict__ deg,
                                               float* __restrict__ dinv) {
    __shared__ int s[256];
    int t = threadIdx.x, b = blockIdx.x;
    int nd = b * 256 + t;
    if (nd < N_NODES) dinv[nd] = rsqrtf(1.0f + deg[nd]);
    int v = gh[t * NBUCK + b];
    s[t] = v;
    __syncthreads();
    int x = v;
    for (int off = 1; off < 256; off <<= 1) {
        int u = (t >= off) ? s[t - off] : 0;
        __syncthreads();
        x += u; s[t] = x;
        __syncthreads();
    }
    gh[t * NBUCK + b] = x - v;            // exclusive within bucket
    if (t == 255) total[b] = x;
}

// ---------------- bucket scatter (LDS cursors; bucket bases recomputed locally) ----------------

__global__ __launch_bounds__(256) void bucket_k(const int* __restrict__ src,
        const int* __restrict__ dst, const float* __restrict__ ew,
        const int* __restrict__ gh, const int* __restrict__ total,
        int2* __restrict__ bkt) {
    __shared__ int cur[256];
    __shared__ int sc[256];
    int t = threadIdx.x, b = blockIdx.x;
    int v = (t < NBUCK) ? total[t] : 0;
    sc[t] = v;
    __syncthreads();
    int x = v;
    for (int off = 1; off < 256; off <<= 1) {
        int u = (t >= off) ? sc[t - off] : 0;
        __syncthreads();
        x += u; sc[t] = x;
        __syncthreads();
    }
    if (t < NBUCK) cur[t] = (x - v) + gh[b * NBUCK + t];   // bbase[t] + within-bucket offset
    __syncthreads();
    int e0 = b * EPB;
    for (int j = t; j < EPB; j += 256) {
        int d = dst[e0 + j];
        int pos = atomicAdd(&cur[d >> 8], 1);
        bkt[pos] = make_int2(src[e0 + j] | (d << 16), __float_as_int(ew[e0 + j]));
    }
}

// ---------------- finalize: per-bucket dst sort + rowptr + premultiplied edge norm ----------------
// ev.y = ew * dinv[src] * dinv[dst]  (agg kernels no longer gather dinv per edge)

__global__ __launch_bounds__(256) void final_k(const int2* __restrict__ bkt,
        const int* __restrict__ total, const float* __restrict__ dinv,
        int2* __restrict__ ev, int* __restrict__ rowptr) {
    __shared__ int   cnt[256];
    __shared__ int   s[256];
    __shared__ float dloc[256];
    int t = threadIdx.x, b = blockIdx.x;

    int nd = b * 256 + t;
    dloc[t] = (nd < N_NODES) ? dinv[nd] : 0.f;
    cnt[t] = 0;

    // local exclusive scan of total[] -> this bucket's base
    int v = (t < NBUCK) ? total[t] : 0;
    s[t] = v;
    __syncthreads();
    int x = v;
    for (int off = 1; off < 256; off <<= 1) {
        int u = (t >= off) ? s[t - off] : 0;
        __syncthreads();
        x += u; s[t] = x;
        __syncthreads();
    }
    int base = (b == 0) ? 0 : s[b - 1];
    int cntb = total[b];
    __syncthreads();

    // pass 1: per-dst counts within bucket
    for (int j = t; j < cntb; j += 256)
        atomicAdd(&cnt[(bkt[base + j].x >> 16) & 255], 1);
    __syncthreads();

    // scan counts -> within-bucket offsets
    int v2 = cnt[t];
    s[t] = v2;
    __syncthreads();
    int x2 = v2;
    for (int off = 1; off < 256; off <<= 1) {
        int u = (t >= off) ? s[t - off] : 0;
        __syncthreads();
        x2 += u; s[t] = x2;
        __syncthreads();
    }
    int off_t = x2 - v2;
    if (nd < N_NODES) rowptr[nd] = base + off_t;
    if (b == 0 && t == 0) rowptr[N_NODES] = N_EDGES;
    s[t] = off_t;
    __syncthreads();

    // pass 2: scatter sorted records with premultiplied norm
    for (int j = t; j < cntb; j += 256) {
        int2 r = bkt[base + j];
        int bin  = (r.x >> 16) & 255;
        int sidx = r.x & 0xFFFF;
        float wv = __int_as_float(r.y) * dinv[sidx] * dloc[bin];
        int p = atomicAdd(&s[bin], 1);
        ev[base + p] = make_int2(sidx, __float_as_int(wv));
    }
}

// ---------------- Aggregation, 128 half features ----------------
// out_i = relu( dinv_i^2 * h_i + sum_e wv_e * h[src_e] + bias ), half out
// (wv_e premultiplied = ew*dinv[src]*dinv[dst])

__global__ __launch_bounds__(256) void agg128_k(const __half* __restrict__ H,
        const int2* __restrict__ ev, const int* __restrict__ rowptr,
        const float* __restrict__ dinv, const float* __restrict__ bias,
        __half* __restrict__ out) {
    int lane = threadIdx.x & 63;
    int node = __builtin_amdgcn_readfirstlane(blockIdx.x * 4 + (threadIdx.x >> 6));
    if (node >= N_NODES) return;
    const __half2* __restrict__ H2 = (const __half2*)H;
    float di = dinv[node];
    float dii = di * di;
    float2 hs = __half22float2(H2[(size_t)node * 64 + lane]);
    float ax = dii * hs.x, ay = dii * hs.y;
    int e0 = rowptr[node], e1 = rowptr[node + 1];
    int e = e0;
    for (; e + 4 <= e1; e += 4) {
        int2 p0 = ev[e + 0];
        int2 p1 = ev[e + 1];
        int2 p2 = ev[e + 2];
        int2 p3 = ev[e + 3];
        float2 g0 = __half22float2(H2[(size_t)p0.x * 64 + lane]);
        float2 g1 = __half22float2(H2[(size_t)p1.x * 64 + lane]);
        float2 g2 = __half22float2(H2[(size_t)p2.x * 64 + lane]);
        float2 g3 = __half22float2(H2[(size_t)p3.x * 64 + lane]);
        float v0 = __int_as_float(p0.y);
        float v1 = __int_as_float(p1.y);
        float v2 = __int_as_float(p2.y);
        float v3 = __int_as_float(p3.y);
        ax = fmaf(v0, g0.x, ax); ay = fmaf(v0, g0.y, ay);
        ax = fmaf(v1, g1.x, ax); ay = fmaf(v1, g1.y, ay);
        ax = fmaf(v2, g2.x, ax); ay = fmaf(v2, g2.y, ay);
        ax = fmaf(v3, g3.x, ax); ay = fmaf(v3, g3.y, ay);
    }
    for (; e < e1; e++) {
        int2 p = ev[e];
        float v = __int_as_float(p.y);
        float2 g = __half22float2(H2[(size_t)p.x * 64 + lane]);
        ax = fmaf(v, g.x, ax);
        ay = fmaf(v, g.y, ay);
    }
    float2 b = *(const float2*)&bias[2 * lane];
    ax = fmaxf(ax + b.x, 0.f);
    ay = fmaxf(ay + b.y, 0.f);
    ((__half2*)out)[(size_t)node * 64 + lane] = __float22half2_rn(make_float2(ax, ay));
}

// ---------------- Aggregation, 40 half features -> fp32 out with bias ----------------
// Two 32-lane halves each take alternate edges (halves the serial edge loop);
// cross-half reduce via shfl_xor(32) at the end.

__global__ __launch_bounds__(256) void agg40_k(const __half* __restrict__ Y,
        const int2* __restrict__ ev, const int* __restrict__ rowptr,
        const float* __restrict__ dinv, const float* __restrict__ bias,
        float* __restrict__ out) {
    int lane = threadIdx.x & 63;
    int node = __builtin_amdgcn_readfirstlane(blockIdx.x * 4 + (threadIdx.x >> 6));
    if (node >= N_NODES) return;
    const __half2* __restrict__ Y2 = (const __half2*)Y;
    int h = lane >> 5;                         // half-wave 0/1
    int l = lane & 31;
    int f = (l < 20) ? l : 0;                  // feature pair index
    float di = dinv[node];
    float dii = di * di;
    float ax = 0.f, ay = 0.f;
    if (h == 0) {
        float2 ys = __half22float2(Y2[(size_t)node * 20 + f]);
        ax = dii * ys.x; ay = dii * ys.y;
    }
    int e0 = rowptr[node], e1 = rowptr[node + 1];
    int e = e0;
    for (; e + 4 <= e1; e += 4) {              // each half-wave: 2 of the 4 edges
        int2 p0 = ev[e + h * 2 + 0];
        int2 p1 = ev[e + h * 2 + 1];
        float2 g0 = __half22float2(Y2[(size_t)p0.x * 20 + f]);
        float2 g1 = __half22float2(Y2[(size_t)p1.x * 20 + f]);
        float v0 = __int_as_float(p0.y);
        float v1 = __int_as_float(p1.y);
        ax = fmaf(v0, g0.x, ax); ay = fmaf(v0, g0.y, ay);
        ax = fmaf(v1, g1.x, ax); ay = fmaf(v1, g1.y, ay);
    }
    for (int ee = e + h; ee < e1; ee += 2) {   // remainder split across halves
        int2 p = ev[ee];
        float v = __int_as_float(p.y);
        float2 g = __half22float2(Y2[(size_t)p.x * 20 + f]);
        ax = fmaf(v, g.x, ax);
        ay = fmaf(v, g.y, ay);
    }
    ax += __shfl_xor(ax, 32);
    ay += __shfl_xor(ay, 32);
    if (lane < 20) {
        float2 b = *(const float2*)&bias[2 * lane];
        float2 o;
        o.x = ax + b.x;
        o.y = ay + b.y;
        *(float2*)&out[(size_t)node * 40 + 2 * lane] = o;
    }
}

// ---------------- launch ----------------

extern "C" void kernel_launch(void* const* d_in, const int* in_sizes, int n_in,
                              void* d_out, int out_size, void* d_ws, size_t ws_size,
                              hipStream_t stream) {
    const float* x  = (const float*)d_in[0];
    const int*   ei = (const int*)d_in[1];
    const int*   src = ei;
    const int*   dst = ei + N_EDGES;
    const float* ew = (const float*)d_in[2];
    const float* W1 = (const float*)d_in[3];
    const float* b1 = (const float*)d_in[4];
    const float* W2 = (const float*)d_in[5];
    const float* b2 = (const float*)d_in[6];
    const float* W3 = (const float*)d_in[7];
    const float* b3 = (const float*)d_in[8];
    float* out = (float*)d_out;

    char* w = (char*)d_ws;
    auto alloc = [&](size_t bytes) {
        char* p = w;
        w += (bytes + 255) & ~(size_t)255;
        return p;
    };
    float*     dinv   = (float*)    alloc((size_t)N_NODES * 4);
    float*     deg    = (float*)    alloc((size_t)N_NODES * 4);
    int*       rowptr = (int*)      alloc((size_t)(N_NODES + 1) * 4);
    int*       gh     = (int*)      alloc((size_t)NBLK * NBUCK * 4);
    int*       total  = (int*)      alloc((size_t)NBUCK * 4);
    int2*      bkt    = (int2*)     alloc((size_t)N_EDGES * 8);
    int2*      ev     = (int2*)     alloc((size_t)N_EDGES * 8);
    __half*    hbuf   = (__half*)   alloc((size_t)N_NODES * 128 * 2);
    __half*    abuf   = (__half*)   alloc((size_t)N_NODES * 128 * 2);
    __half*    ybuf   = (__half*)   alloc((size_t)N_NODES * 40 * 2);
    _Float16*  Wt1    = (_Float16*) alloc((size_t)128 * 128 * 2);
    _Float16*  Wt2    = (_Float16*) alloc((size_t)128 * 128 * 2);
    _Float16*  Wt3    = (_Float16*) alloc((size_t)48 * 128 * 2);

    constexpr int GA = (N_NODES + 3) / 4;

    wconv_k<<<196, 256, 0, stream>>>(W1, W2, W3, Wt1, Wt2, Wt3, deg);
    // fused: P1 bucket histogram + deg atomics + gemm1 (x @ W1 -> hbuf half, MFMA)
    gemm_mfma_k<float, 128, 8, true><<<NBLK + GBM, 256, 0, stream>>>(x, Wt1, hbuf, dst, gh, ew, deg);
    scan1_k<<<NBUCK, 256, 0, stream>>>(gh, total, deg, dinv);
    bucket_k<<<NBLK, 256, 0, stream>>>(src, dst, ew, gh, total, bkt);
    final_k<<<NBUCK, 256, 0, stream>>>(bkt, total, dinv, ev, rowptr);

    agg128_k<<<GA, 256, 0, stream>>>(hbuf, ev, rowptr, dinv, b1, abuf);
    gemm_mfma_k<__half, 128, 8, false><<<GBM, 256, 0, stream>>>(abuf, Wt2, hbuf, nullptr, nullptr, nullptr, nullptr);
    agg128_k<<<GA, 256, 0, stream>>>(hbuf, ev, rowptr, dinv, b2, abuf);
    gemm_mfma_k<__half, 40, 3, false><<<GBM, 256, 0, stream>>>(abuf, Wt3, ybuf, nullptr, nullptr, nullptr, nullptr);
    agg40_k<<<GA, 256, 0, stream>>>(ybuf, ev, rowptr, dinv, b3, out);
}

// Round 4
// 257.008 us; speedup vs baseline: 1.0458x; 1.0458x over previous
//
#include <hip/hip_runtime.h>
#include <hip/hip_fp16.h>

constexpr int N_NODES = 50000;
constexpr int N_EDGES = 640000;

constexpr int NBLK  = 256;                    // edge-chunk blocks
constexpr int EPB   = N_EDGES / NBLK;         // 2500 (exact)
constexpr int NBUCK = (N_NODES + 255) / 256;  // 196 buckets of 256 dst each
constexpr int GBM   = (N_NODES + 63) / 64;    // mfma-gemm blocks (64 rows each)

typedef _Float16 half8  __attribute__((ext_vector_type(8)));
typedef _Float16 half4v __attribute__((ext_vector_type(4)));
typedef float    floatx4 __attribute__((ext_vector_type(4)));

// ---------------- W -> W^T fp16 conversion (one-time, tiny) ----------------

__global__ void wconv_k(const float* __restrict__ W1, const float* __restrict__ W2,
                        const float* __restrict__ W3, _Float16* __restrict__ Wt1,
                        _Float16* __restrict__ Wt2, _Float16* __restrict__ Wt3) {
    int i = blockIdx.x * 256 + threadIdx.x;
    if (i < 16384) {
        int n = i >> 7, k = i & 127;
        Wt1[n * 128 + k] = (_Float16)W1[k * 128 + n];
    } else if (i < 32768) {
        int j = i - 16384; int n = j >> 7, k = j & 127;
        Wt2[n * 128 + k] = (_Float16)W2[k * 128 + n];
    } else if (i < 32768 + 6144) {
        int j = i - 32768; int n = j >> 7, k = j & 127;
        Wt3[n * 128 + k] = (_Float16)((n < 40) ? W3[k * 40 + n] : 0.f);
    }
}

// ---------------- MFMA GEMM: H[N,F_OUT] = X[N,128] @ W, fp16 in/out, fp32 acc ----------------
// 64 rows/block, 4 waves, each wave 16 rows x F_OUT cols via 16x16x32 f16 MFMA.
// A from LDS (pad-136 rows, ds_read_b128); B from global Wt[n][k] (L1-resident).
// FUSE_HIST: blocks [0,NBLK) do the LDS bucket histogram (NO global atomics —
// round-2 profile showed 640k global fp32 atomicAdds cost ~30us + ~20MB HBM writes).

template<typename TIN, int F_OUT, int NT, bool FUSE_HIST>
__global__ __launch_bounds__(256) void gemm_mfma_k(const TIN* __restrict__ X,
        const _Float16* __restrict__ Wt, __half* __restrict__ H,
        const int* __restrict__ dst, int* __restrict__ gh) {
    if constexpr (FUSE_HIST) {
        if (blockIdx.x < NBLK) {
            __shared__ int lh[256];
            int t = threadIdx.x, b = blockIdx.x;
            lh[t] = 0;
            __syncthreads();
            int e0 = b * EPB;
            for (int j = t; j < EPB; j += 256)
                atomicAdd(&lh[dst[e0 + j] >> 8], 1);
            __syncthreads();
            if (t < NBUCK) gh[b * NBUCK + t] = lh[t];
            return;
        }
    }
    int bid = FUSE_HIST ? (int)blockIdx.x - NBLK : (int)blockIdx.x;

    __shared__ _Float16 Xs[64 * 136];      // 64 rows, stride 136 (16B-aligned pad)
    int tid = threadIdx.x;
    int row0 = bid * 64;

    if constexpr (sizeof(TIN) == 4) {      // fp32 input -> convert
        for (int idx = tid; idx < 2048; idx += 256) {
            int r = idx >> 5, c4 = idx & 31;
            float4 v = {0.f, 0.f, 0.f, 0.f};
            if (row0 + r < N_NODES)
                v = *(const float4*)((const float*)X + (size_t)(row0 + r) * 128 + c4 * 4);
            half4v h;
            h[0] = (_Float16)v.x; h[1] = (_Float16)v.y;
            h[2] = (_Float16)v.z; h[3] = (_Float16)v.w;
            *(half4v*)&Xs[r * 136 + c4 * 4] = h;
        }
    } else {                               // fp16 input -> raw copy
        for (int idx = tid; idx < 1024; idx += 256) {
            int r = idx >> 4, c8 = idx & 15;
            int4 v = {0, 0, 0, 0};
            if (row0 + r < N_NODES)
                v = *(const int4*)((const __half*)X + (size_t)(row0 + r) * 128 + c8 * 8);
            *(int4*)&Xs[r * 136 + c8 * 8] = v;
        }
    }
    __syncthreads();

    int lane = tid & 63;
    int wv   = tid >> 6;                   // wave 0..3 -> rows wv*16..+15
    int m    = lane & 15;
    int q    = lane >> 4;

    half8 af[4];
    #pragma unroll
    for (int kt = 0; kt < 4; kt++)
        af[kt] = *(const half8*)&Xs[(wv * 16 + m) * 136 + kt * 32 + q * 8];

    floatx4 acc[NT];
    #pragma unroll
    for (int nt = 0; nt < NT; nt++) { acc[nt][0] = 0.f; acc[nt][1] = 0.f; acc[nt][2] = 0.f; acc[nt][3] = 0.f; }

    #pragma unroll
    for (int nt = 0; nt < NT; nt++) {
        const _Float16* wp = Wt + (size_t)(nt * 16 + m) * 128 + q * 8;
        half8 b0 = *(const half8*)(wp);
        half8 b1 = *(const half8*)(wp + 32);
        half8 b2 = *(const half8*)(wp + 64);
        half8 b3 = *(const half8*)(wp + 96);
        acc[nt] = __builtin_amdgcn_mfma_f32_16x16x32_f16(af[0], b0, acc[nt], 0, 0, 0);
        acc[nt] = __builtin_amdgcn_mfma_f32_16x16x32_f16(af[1], b1, acc[nt], 0, 0, 0);
        acc[nt] = __builtin_amdgcn_mfma_f32_16x16x32_f16(af[2], b2, acc[nt], 0, 0, 0);
        acc[nt] = __builtin_amdgcn_mfma_f32_16x16x32_f16(af[3], b3, acc[nt], 0, 0, 0);
    }

    // C -> own wave's LDS region (rows wv*16..+15 only; no cross-wave hazard)
    #pragma unroll
    for (int nt = 0; nt < NT; nt++) {
        #pragma unroll
        for (int r = 0; r < 4; r++)
            Xs[(wv * 16 + q * 4 + r) * 136 + nt * 16 + m] = (_Float16)acc[nt][r];
    }

    // coalesced copy-out of own region
    if constexpr (F_OUT == 128) {
        for (int g = lane; g < 256; g += 64) {
            int r = g >> 4, c8 = g & 15;
            int row = row0 + wv * 16 + r;
            if (row < N_NODES)
                *(int4*)((__half*)H + (size_t)row * 128 + c8 * 8) =
                    *(const int4*)&Xs[(wv * 16 + r) * 136 + c8 * 8];
        }
    } else {                               // F_OUT = 40: 5 int4 per row
        for (int g = lane; g < 80; g += 64) {
            int r = g / 5, seg = g - r * 5;
            int row = row0 + wv * 16 + r;
            if (row < N_NODES)
                *(int4*)((__half*)H + (size_t)row * 40 + seg * 8) =
                    *(const int4*)&Xs[(wv * 16 + r) * 136 + seg * 8];
        }
    }
}

// ---------------- scan1: per-bucket exclusive prefix over edge-chunks ----------------

__global__ __launch_bounds__(256) void scan1_k(int* __restrict__ gh, int* __restrict__ total) {
    __shared__ int s[256];
    int t = threadIdx.x, b = blockIdx.x;
    int v = gh[t * NBUCK + b];
    s[t] = v;
    __syncthreads();
    int x = v;
    for (int off = 1; off < 256; off <<= 1) {
        int u = (t >= off) ? s[t - off] : 0;
        __syncthreads();
        x += u; s[t] = x;
        __syncthreads();
    }
    gh[t * NBUCK + b] = x - v;            // exclusive within bucket
    if (t == 255) total[b] = x;
}

// ---------------- bucket scatter (LDS cursors; bucket bases recomputed locally) ----------------

__global__ __launch_bounds__(256) void bucket_k(const int* __restrict__ src,
        const int* __restrict__ dst, const float* __restrict__ ew,
        const int* __restrict__ gh, const int* __restrict__ total,
        int2* __restrict__ bkt) {
    __shared__ int cur[256];
    __shared__ int sc[256];
    int t = threadIdx.x, b = blockIdx.x;
    int v = (t < NBUCK) ? total[t] : 0;
    sc[t] = v;
    __syncthreads();
    int x = v;
    for (int off = 1; off < 256; off <<= 1) {
        int u = (t >= off) ? sc[t - off] : 0;
        __syncthreads();
        x += u; sc[t] = x;
        __syncthreads();
    }
    if (t < NBUCK) cur[t] = (x - v) + gh[b * NBUCK + t];   // bbase[t] + within-bucket offset
    __syncthreads();
    int e0 = b * EPB;
    for (int j = t; j < EPB; j += 256) {
        int d = dst[e0 + j];
        int pos = atomicAdd(&cur[d >> 8], 1);
        bkt[pos] = make_int2(src[e0 + j] | (d << 16), __float_as_int(ew[e0 + j]));
    }
}

// ---------------- finalize: per-bucket dst sort + rowptr + deg/dinv + dst-side norm ----------------
// Computes deg via per-bucket LDS wsum (cheap — data already dst-sorted by bucket).
// ev.y = ew * dinv[dst]; the src-side dinv factor is folded in by the FIRST agg128
// (which gathers dinv[src] once and writes the full product back to ev.y).

__global__ __launch_bounds__(256) void final_k(const int2* __restrict__ bkt,
        const int* __restrict__ total, int2* __restrict__ ev,
        int* __restrict__ rowptr, float* __restrict__ dinv) {
    __shared__ int   cnt[256];
    __shared__ float wsum[256];
    __shared__ int   s[256];
    int t = threadIdx.x, b = blockIdx.x;

    cnt[t] = 0; wsum[t] = 0.f;

    // local exclusive scan of total[] -> this bucket's base
    int v = (t < NBUCK) ? total[t] : 0;
    s[t] = v;
    __syncthreads();
    int x = v;
    for (int off = 1; off < 256; off <<= 1) {
        int u = (t >= off) ? s[t - off] : 0;
        __syncthreads();
        x += u; s[t] = x;
        __syncthreads();
    }
    int base = (b == 0) ? 0 : s[b - 1];
    int cntb = total[b];
    __syncthreads();

    // pass 1: per-dst counts + weighted degree within bucket
    for (int j = t; j < cntb; j += 256) {
        int2 r = bkt[base + j];
        int bin = (r.x >> 16) & 255;
        atomicAdd(&cnt[bin], 1);
        atomicAdd(&wsum[bin], __int_as_float(r.y));
    }
    __syncthreads();

    // scan counts -> within-bucket offsets
    int v2 = cnt[t];
    s[t] = v2;
    __syncthreads();
    int x2 = v2;
    for (int off = 1; off < 256; off <<= 1) {
        int u = (t >= off) ? s[t - off] : 0;
        __syncthreads();
        x2 += u; s[t] = x2;
        __syncthreads();
    }
    int off_t = x2 - v2;
    int nd = b * 256 + t;
    float dv = rsqrtf(1.0f + wsum[t]);     // self-loop contributes +1
    if (nd < N_NODES) {
        rowptr[nd] = base + off_t;
        dinv[nd]   = dv;
    }
    if (b == 0 && t == 0) rowptr[N_NODES] = N_EDGES;
    wsum[t] = dv;                          // wsum[t] only touched by thread t — safe overwrite
    s[t] = off_t;
    __syncthreads();

    // pass 2: scatter sorted records with dst-side norm premultiplied
    for (int j = t; j < cntb; j += 256) {
        int2 r = bkt[base + j];
        int bin  = (r.x >> 16) & 255;
        int sidx = r.x & 0xFFFF;
        float wv = __int_as_float(r.y) * wsum[bin];   // ew * dinv[dst]
        int p = atomicAdd(&s[bin], 1);
        ev[base + p] = make_int2(sidx, __float_as_int(wv));
    }
}

// ---------------- Aggregation, 128 half features ----------------
// out_i = relu( dinv_i^2 * h_i + sum_e wv_e * h[src_e] + bias ), half out
// PREMUL (first agg only): ev.y holds ew*dinv[dst]; gather dinv[src], use the
// full product AND write it back so later aggs read fully premultiplied weights.
// Writeback hazard-free: each ev[e] belongs to exactly one node = one wave;
// all 64 lanes load ev[e] in lockstep before lane 0's store.

template<bool PREMUL>
__global__ __launch_bounds__(256) void agg128_k(const __half* __restrict__ H,
        int2* __restrict__ ev, const int* __restrict__ rowptr,
        const float* __restrict__ dinv, const float* __restrict__ bias,
        __half* __restrict__ out) {
    int lane = threadIdx.x & 63;
    int node = __builtin_amdgcn_readfirstlane(blockIdx.x * 4 + (threadIdx.x >> 6));
    if (node >= N_NODES) return;
    const __half2* __restrict__ H2 = (const __half2*)H;
    float di = dinv[node];
    float dii = di * di;
    float2 hs = __half22float2(H2[(size_t)node * 64 + lane]);
    float ax = dii * hs.x, ay = dii * hs.y;
    int e0 = rowptr[node], e1 = rowptr[node + 1];
    int e = e0;
    for (; e + 4 <= e1; e += 4) {
        int2 p0 = ev[e + 0];
        int2 p1 = ev[e + 1];
        int2 p2 = ev[e + 2];
        int2 p3 = ev[e + 3];
        float v0 = __int_as_float(p0.y);
        float v1 = __int_as_float(p1.y);
        float v2 = __int_as_float(p2.y);
        float v3 = __int_as_float(p3.y);
        if constexpr (PREMUL) {
            v0 *= dinv[p0.x]; v1 *= dinv[p1.x];
            v2 *= dinv[p2.x]; v3 *= dinv[p3.x];
            if (lane == 0) {
                ev[e + 0].y = __float_as_int(v0);
                ev[e + 1].y = __float_as_int(v1);
                ev[e + 2].y = __float_as_int(v2);
                ev[e + 3].y = __float_as_int(v3);
            }
        }
        float2 g0 = __half22float2(H2[(size_t)p0.x * 64 + lane]);
        float2 g1 = __half22float2(H2[(size_t)p1.x * 64 + lane]);
        float2 g2 = __half22float2(H2[(size_t)p2.x * 64 + lane]);
        float2 g3 = __half22float2(H2[(size_t)p3.x * 64 + lane]);
        ax = fmaf(v0, g0.x, ax); ay = fmaf(v0, g0.y, ay);
        ax = fmaf(v1, g1.x, ax); ay = fmaf(v1, g1.y, ay);
        ax = fmaf(v2, g2.x, ax); ay = fmaf(v2, g2.y, ay);
        ax = fmaf(v3, g3.x, ax); ay = fmaf(v3, g3.y, ay);
    }
    for (; e < e1; e++) {
        int2 p = ev[e];
        float v = __int_as_float(p.y);
        if constexpr (PREMUL) {
            v *= dinv[p.x];
            if (lane == 0) ev[e].y = __float_as_int(v);
        }
        float2 g = __half22float2(H2[(size_t)p.x * 64 + lane]);
        ax = fmaf(v, g.x, ax);
        ay = fmaf(v, g.y, ay);
    }
    float2 b = *(const float2*)&bias[2 * lane];
    ax = fmaxf(ax + b.x, 0.f);
    ay = fmaxf(ay + b.y, 0.f);
    ((__half2*)out)[(size_t)node * 64 + lane] = __float22half2_rn(make_float2(ax, ay));
}

// ---------------- Aggregation, 40 half features -> fp32 out with bias ----------------
// Two 32-lane halves each take alternate edges (halves the serial edge loop);
// cross-half reduce via shfl_xor(32) at the end. ev.y fully premultiplied.

__global__ __launch_bounds__(256) void agg40_k(const __half* __restrict__ Y,
        const int2* __restrict__ ev, const int* __restrict__ rowptr,
        const float* __restrict__ dinv, const float* __restrict__ bias,
        float* __restrict__ out) {
    int lane = threadIdx.x & 63;
    int node = __builtin_amdgcn_readfirstlane(blockIdx.x * 4 + (threadIdx.x >> 6));
    if (node >= N_NODES) return;
    const __half2* __restrict__ Y2 = (const __half2*)Y;
    int h = lane >> 5;                         // half-wave 0/1
    int l = lane & 31;
    int f = (l < 20) ? l : 0;                  // feature pair index
    float di = dinv[node];
    float dii = di * di;
    float ax = 0.f, ay = 0.f;
    if (h == 0) {
        float2 ys = __half22float2(Y2[(size_t)node * 20 + f]);
        ax = dii * ys.x; ay = dii * ys.y;
    }
    int e0 = rowptr[node], e1 = rowptr[node + 1];
    int e = e0;
    for (; e + 4 <= e1; e += 4) {              // each half-wave: 2 of the 4 edges
        int2 p0 = ev[e + h * 2 + 0];
        int2 p1 = ev[e + h * 2 + 1];
        float2 g0 = __half22float2(Y2[(size_t)p0.x * 20 + f]);
        float2 g1 = __half22float2(Y2[(size_t)p1.x * 20 + f]);
        float v0 = __int_as_float(p0.y);
        float v1 = __int_as_float(p1.y);
        ax = fmaf(v0, g0.x, ax); ay = fmaf(v0, g0.y, ay);
        ax = fmaf(v1, g1.x, ax); ay = fmaf(v1, g1.y, ay);
    }
    for (int ee = e + h; ee < e1; ee += 2) {   // remainder split across halves
        int2 p = ev[ee];
        float v = __int_as_float(p.y);
        float2 g = __half22float2(Y2[(size_t)p.x * 20 + f]);
        ax = fmaf(v, g.x, ax);
        ay = fmaf(v, g.y, ay);
    }
    ax += __shfl_xor(ax, 32);
    ay += __shfl_xor(ay, 32);
    if (lane < 20) {
        float2 b = *(const float2*)&bias[2 * lane];
        float2 o;
        o.x = ax + b.x;
        o.y = ay + b.y;
        *(float2*)&out[(size_t)node * 40 + 2 * lane] = o;
    }
}

// ---------------- launch ----------------

extern "C" void kernel_launch(void* const* d_in, const int* in_sizes, int n_in,
                              void* d_out, int out_size, void* d_ws, size_t ws_size,
                              hipStream_t stream) {
    const float* x  = (const float*)d_in[0];
    const int*   ei = (const int*)d_in[1];
    const int*   src = ei;
    const int*   dst = ei + N_EDGES;
    const float* ew = (const float*)d_in[2];
    const float* W1 = (const float*)d_in[3];
    const float* b1 = (const float*)d_in[4];
    const float* W2 = (const float*)d_in[5];
    const float* b2 = (const float*)d_in[6];
    const float* W3 = (const float*)d_in[7];
    const float* b3 = (const float*)d_in[8];
    float* out = (float*)d_out;

    char* w = (char*)d_ws;
    auto alloc = [&](size_t bytes) {
        char* p = w;
        w += (bytes + 255) & ~(size_t)255;
        return p;
    };
    float*     dinv   = (float*)    alloc((size_t)N_NODES * 4);
    int*       rowptr = (int*)      alloc((size_t)(N_NODES + 1) * 4);
    int*       gh     = (int*)      alloc((size_t)NBLK * NBUCK * 4);
    int*       total  = (int*)      alloc((size_t)NBUCK * 4);
    int2*      bkt    = (int2*)     alloc((size_t)N_EDGES * 8);
    int2*      ev     = (int2*)     alloc((size_t)N_EDGES * 8);
    __half*    hbuf   = (__half*)   alloc((size_t)N_NODES * 128 * 2);
    __half*    abuf   = (__half*)   alloc((size_t)N_NODES * 128 * 2);
    __half*    ybuf   = (__half*)   alloc((size_t)N_NODES * 40 * 2);
    _Float16*  Wt1    = (_Float16*) alloc((size_t)128 * 128 * 2);
    _Float16*  Wt2    = (_Float16*) alloc((size_t)128 * 128 * 2);
    _Float16*  Wt3    = (_Float16*) alloc((size_t)48 * 128 * 2);

    constexpr int GA = (N_NODES + 3) / 4;

    wconv_k<<<152, 256, 0, stream>>>(W1, W2, W3, Wt1, Wt2, Wt3);
    // fused: P1 bucket histogram + gemm1 (x @ W1 -> hbuf half, MFMA)
    gemm_mfma_k<float, 128, 8, true><<<NBLK + GBM, 256, 0, stream>>>(x, Wt1, hbuf, dst, gh);
    scan1_k<<<NBUCK, 256, 0, stream>>>(gh, total);
    bucket_k<<<NBLK, 256, 0, stream>>>(src, dst, ew, gh, total, bkt);
    final_k<<<NBUCK, 256, 0, stream>>>(bkt, total, ev, rowptr, dinv);

    agg128_k<true ><<<GA, 256, 0, stream>>>(hbuf, ev, rowptr, dinv, b1, abuf);
    gemm_mfma_k<__half, 128, 8, false><<<GBM, 256, 0, stream>>>(abuf, Wt2, hbuf, nullptr, nullptr);
    agg128_k<false><<<GA, 256, 0, stream>>>(hbuf, ev, rowptr, dinv, b2, abuf);
    gemm_mfma_k<__half, 40, 3, false><<<GBM, 256, 0, stream>>>(abuf, Wt3, ybuf, nullptr, nullptr);
    agg40_k<<<GA, 256, 0, stream>>>(ybuf, ev, rowptr, dinv, b3, out);
}

// Round 5
// 244.503 us; speedup vs baseline: 1.0993x; 1.0511x over previous
//
#include <hip/hip_runtime.h>
#include <hip/hip_fp16.h>

constexpr int N_NODES = 50000;
constexpr int N_EDGES = 640000;

constexpr int NBLK  = 256;                    // edge-chunk blocks
constexpr int EPB   = N_EDGES / NBLK;         // 2500 (exact)
constexpr int NBUCK = (N_NODES + 255) / 256;  // 196 buckets of 256 dst each
constexpr int GBM   = (N_NODES + 63) / 64;    // mfma-gemm blocks (64 rows each)

typedef _Float16 half8  __attribute__((ext_vector_type(8)));
typedef _Float16 half4v __attribute__((ext_vector_type(4)));
typedef float    floatx4 __attribute__((ext_vector_type(4)));

// ---------------- W -> W^T fp16 conversion (one-time, tiny) ----------------

__global__ void wconv_k(const float* __restrict__ W1, const float* __restrict__ W2,
                        const float* __restrict__ W3, _Float16* __restrict__ Wt1,
                        _Float16* __restrict__ Wt2, _Float16* __restrict__ Wt3) {
    int i = blockIdx.x * 256 + threadIdx.x;
    if (i < 16384) {
        int n = i >> 7, k = i & 127;
        Wt1[n * 128 + k] = (_Float16)W1[k * 128 + n];
    } else if (i < 32768) {
        int j = i - 16384; int n = j >> 7, k = j & 127;
        Wt2[n * 128 + k] = (_Float16)W2[k * 128 + n];
    } else if (i < 32768 + 6144) {
        int j = i - 32768; int n = j >> 7, k = j & 127;
        Wt3[n * 128 + k] = (_Float16)((n < 40) ? W3[k * 40 + n] : 0.f);
    }
}

// ---------------- MFMA GEMM (layer 1 only): H = X[N,128] @ W, fp32 in, fp16 out ----------------
// FUSE_HIST: blocks [0,NBLK) do the LDS bucket histogram (no global atomics).

template<typename TIN, int F_OUT, int NT, bool FUSE_HIST>
__global__ __launch_bounds__(256) void gemm_mfma_k(const TIN* __restrict__ X,
        const _Float16* __restrict__ Wt, __half* __restrict__ H,
        const int* __restrict__ dst, int* __restrict__ gh) {
    if constexpr (FUSE_HIST) {
        if (blockIdx.x < NBLK) {
            __shared__ int lh[256];
            int t = threadIdx.x, b = blockIdx.x;
            lh[t] = 0;
            __syncthreads();
            int e0 = b * EPB;
            for (int j = t; j < EPB; j += 256)
                atomicAdd(&lh[dst[e0 + j] >> 8], 1);
            __syncthreads();
            if (t < NBUCK) gh[b * NBUCK + t] = lh[t];
            return;
        }
    }
    int bid = FUSE_HIST ? (int)blockIdx.x - NBLK : (int)blockIdx.x;

    __shared__ _Float16 Xs[64 * 136];      // 64 rows, stride 136 (16B-aligned pad)
    int tid = threadIdx.x;
    int row0 = bid * 64;

    if constexpr (sizeof(TIN) == 4) {      // fp32 input -> convert
        for (int idx = tid; idx < 2048; idx += 256) {
            int r = idx >> 5, c4 = idx & 31;
            float4 v = {0.f, 0.f, 0.f, 0.f};
            if (row0 + r < N_NODES)
                v = *(const float4*)((const float*)X + (size_t)(row0 + r) * 128 + c4 * 4);
            half4v h;
            h[0] = (_Float16)v.x; h[1] = (_Float16)v.y;
            h[2] = (_Float16)v.z; h[3] = (_Float16)v.w;
            *(half4v*)&Xs[r * 136 + c4 * 4] = h;
        }
    } else {                               // fp16 input -> raw copy
        for (int idx = tid; idx < 1024; idx += 256) {
            int r = idx >> 4, c8 = idx & 15;
            int4 v = {0, 0, 0, 0};
            if (row0 + r < N_NODES)
                v = *(const int4*)((const __half*)X + (size_t)(row0 + r) * 128 + c8 * 8);
            *(int4*)&Xs[r * 136 + c8 * 8] = v;
        }
    }
    __syncthreads();

    int lane = tid & 63;
    int wv   = tid >> 6;                   // wave 0..3 -> rows wv*16..+15
    int m    = lane & 15;
    int q    = lane >> 4;

    half8 af[4];
    #pragma unroll
    for (int kt = 0; kt < 4; kt++)
        af[kt] = *(const half8*)&Xs[(wv * 16 + m) * 136 + kt * 32 + q * 8];

    floatx4 acc[NT];
    #pragma unroll
    for (int nt = 0; nt < NT; nt++) { acc[nt][0] = 0.f; acc[nt][1] = 0.f; acc[nt][2] = 0.f; acc[nt][3] = 0.f; }

    #pragma unroll
    for (int nt = 0; nt < NT; nt++) {
        const _Float16* wp = Wt + (size_t)(nt * 16 + m) * 128 + q * 8;
        half8 b0 = *(const half8*)(wp);
        half8 b1 = *(const half8*)(wp + 32);
        half8 b2 = *(const half8*)(wp + 64);
        half8 b3 = *(const half8*)(wp + 96);
        acc[nt] = __builtin_amdgcn_mfma_f32_16x16x32_f16(af[0], b0, acc[nt], 0, 0, 0);
        acc[nt] = __builtin_amdgcn_mfma_f32_16x16x32_f16(af[1], b1, acc[nt], 0, 0, 0);
        acc[nt] = __builtin_amdgcn_mfma_f32_16x16x32_f16(af[2], b2, acc[nt], 0, 0, 0);
        acc[nt] = __builtin_amdgcn_mfma_f32_16x16x32_f16(af[3], b3, acc[nt], 0, 0, 0);
    }

    // C -> own wave's LDS region (rows wv*16..+15 only; no cross-wave hazard)
    #pragma unroll
    for (int nt = 0; nt < NT; nt++) {
        #pragma unroll
        for (int r = 0; r < 4; r++)
            Xs[(wv * 16 + q * 4 + r) * 136 + nt * 16 + m] = (_Float16)acc[nt][r];
    }

    // coalesced copy-out of own region
    for (int g = lane; g < 256; g += 64) {
        int r = g >> 4, c8 = g & 15;
        int row = row0 + wv * 16 + r;
        if (row < N_NODES)
            *(int4*)((__half*)H + (size_t)row * 128 + c8 * 8) =
                *(const int4*)&Xs[(wv * 16 + r) * 136 + c8 * 8];
    }
}

// ---------------- scan1: per-bucket exclusive prefix over edge-chunks ----------------

__global__ __launch_bounds__(256) void scan1_k(int* __restrict__ gh, int* __restrict__ total) {
    __shared__ int s[256];
    int t = threadIdx.x, b = blockIdx.x;
    int v = gh[t * NBUCK + b];
    s[t] = v;
    __syncthreads();
    int x = v;
    for (int off = 1; off < 256; off <<= 1) {
        int u = (t >= off) ? s[t - off] : 0;
        __syncthreads();
        x += u; s[t] = x;
        __syncthreads();
    }
    gh[t * NBUCK + b] = x - v;            // exclusive within bucket
    if (t == 255) total[b] = x;
}

// ---------------- bucket scatter (LDS cursors; bucket bases recomputed locally) ----------------

__global__ __launch_bounds__(256) void bucket_k(const int* __restrict__ src,
        const int* __restrict__ dst, const float* __restrict__ ew,
        const int* __restrict__ gh, const int* __restrict__ total,
        int2* __restrict__ bkt) {
    __shared__ int cur[256];
    __shared__ int sc[256];
    int t = threadIdx.x, b = blockIdx.x;
    int v = (t < NBUCK) ? total[t] : 0;
    sc[t] = v;
    __syncthreads();
    int x = v;
    for (int off = 1; off < 256; off <<= 1) {
        int u = (t >= off) ? sc[t - off] : 0;
        __syncthreads();
        x += u; sc[t] = x;
        __syncthreads();
    }
    if (t < NBUCK) cur[t] = (x - v) + gh[b * NBUCK + t];   // bbase[t] + within-bucket offset
    __syncthreads();
    int e0 = b * EPB;
    for (int j = t; j < EPB; j += 256) {
        int d = dst[e0 + j];
        int pos = atomicAdd(&cur[d >> 8], 1);
        bkt[pos] = make_int2(src[e0 + j] | (d << 16), __float_as_int(ew[e0 + j]));
    }
}

// ---------------- finalize: per-bucket dst sort + rowptr + deg/dinv + dst-side norm ----------------
// ev.y = ew * dinv[dst]; src-side dinv folded in + written back by the first aggemm.

__global__ __launch_bounds__(256) void final_k(const int2* __restrict__ bkt,
        const int* __restrict__ total, int2* __restrict__ ev,
        int* __restrict__ rowptr, float* __restrict__ dinv) {
    __shared__ int   cnt[256];
    __shared__ float wsum[256];
    __shared__ int   s[256];
    int t = threadIdx.x, b = blockIdx.x;

    cnt[t] = 0; wsum[t] = 0.f;

    // local exclusive scan of total[] -> this bucket's base
    int v = (t < NBUCK) ? total[t] : 0;
    s[t] = v;
    __syncthreads();
    int x = v;
    for (int off = 1; off < 256; off <<= 1) {
        int u = (t >= off) ? s[t - off] : 0;
        __syncthreads();
        x += u; s[t] = x;
        __syncthreads();
    }
    int base = (b == 0) ? 0 : s[b - 1];
    int cntb = total[b];
    __syncthreads();

    // pass 1: per-dst counts + weighted degree within bucket
    for (int j = t; j < cntb; j += 256) {
        int2 r = bkt[base + j];
        int bin = (r.x >> 16) & 255;
        atomicAdd(&cnt[bin], 1);
        atomicAdd(&wsum[bin], __int_as_float(r.y));
    }
    __syncthreads();

    // scan counts -> within-bucket offsets
    int v2 = cnt[t];
    s[t] = v2;
    __syncthreads();
    int x2 = v2;
    for (int off = 1; off < 256; off <<= 1) {
        int u = (t >= off) ? s[t - off] : 0;
        __syncthreads();
        x2 += u; s[t] = x2;
        __syncthreads();
    }
    int off_t = x2 - v2;
    int nd = b * 256 + t;
    float dv = rsqrtf(1.0f + wsum[t]);     // self-loop contributes +1
    if (nd < N_NODES) {
        rowptr[nd] = base + off_t;
        dinv[nd]   = dv;
    }
    if (b == 0 && t == 0) rowptr[N_NODES] = N_EDGES;
    wsum[t] = dv;                          // wsum[t] only touched by thread t — safe overwrite
    s[t] = off_t;
    __syncthreads();

    // pass 2: scatter sorted records with dst-side norm premultiplied
    for (int j = t; j < cntb; j += 256) {
        int2 r = bkt[base + j];
        int bin  = (r.x >> 16) & 255;
        int sidx = r.x & 0xFFFF;
        float wv = __int_as_float(r.y) * wsum[bin];   // ew * dinv[dst]
        int p = atomicAdd(&s[bin], 1);
        ev[base + p] = make_int2(sidx, __float_as_int(wv));
    }
}

// ---------------- FUSED aggregate + GEMM ----------------
// Block = one 64-row GEMM tile. 8 waves (512 thr):
//   phase 1: wave wv aggregates nodes [wv*8, wv*8+8): a = relu(dinv^2*h_self +
//            sum wv_e*h[src] + bias), written as fp16 rows into LDS Xs.
//   phase 2: MFMA  Hout_tile = a_tile @ Wt ; waves split as 4 row-groups (rg=wv&3)
//            x 2 column-halves (ch=wv>>2, nt parity). Barriers guard LDS reuse.
// PREMUL (first fusion only): ev.y holds ew*dinv[dst]; fold dinv[src] in and
// write the full product back (lane 0) so later consumers read premultiplied.

template<int F_OUT, int NT, bool PREMUL>
__global__ __launch_bounds__(512) void aggemm_k(const __half* __restrict__ Hin,
        int2* __restrict__ ev, const int* __restrict__ rowptr,
        const float* __restrict__ dinv, const float* __restrict__ bias,
        const _Float16* __restrict__ Wt, __half* __restrict__ Hout) {
    __shared__ _Float16 Xs[64 * 136];
    int tid  = threadIdx.x;
    int lane = tid & 63;
    int wv   = tid >> 6;                   // 0..7
    int row0 = (int)blockIdx.x * 64;
    const __half2* __restrict__ H2 = (const __half2*)Hin;
    float2 bb = *(const float2*)&bias[2 * lane];

    // ---- phase 1: aggregation ----
    for (int r = 0; r < 8; ++r) {
        int lrow = wv * 8 + r;
        int node = __builtin_amdgcn_readfirstlane(row0 + lrow);
        float ax = 0.f, ay = 0.f;
        if (node < N_NODES) {
            float di  = dinv[node];
            float dii = di * di;
            float2 hs = __half22float2(H2[(size_t)node * 64 + lane]);
            ax = dii * hs.x; ay = dii * hs.y;
            int e0 = rowptr[node], e1 = rowptr[node + 1];
            int e = e0;
            for (; e + 4 <= e1; e += 4) {
                int2 p0 = ev[e + 0];
                int2 p1 = ev[e + 1];
                int2 p2 = ev[e + 2];
                int2 p3 = ev[e + 3];
                float v0 = __int_as_float(p0.y);
                float v1 = __int_as_float(p1.y);
                float v2 = __int_as_float(p2.y);
                float v3 = __int_as_float(p3.y);
                if constexpr (PREMUL) {
                    v0 *= dinv[p0.x]; v1 *= dinv[p1.x];
                    v2 *= dinv[p2.x]; v3 *= dinv[p3.x];
                    if (lane == 0) {
                        ev[e + 0].y = __float_as_int(v0);
                        ev[e + 1].y = __float_as_int(v1);
                        ev[e + 2].y = __float_as_int(v2);
                        ev[e + 3].y = __float_as_int(v3);
                    }
                }
                float2 g0 = __half22float2(H2[(size_t)p0.x * 64 + lane]);
                float2 g1 = __half22float2(H2[(size_t)p1.x * 64 + lane]);
                float2 g2 = __half22float2(H2[(size_t)p2.x * 64 + lane]);
                float2 g3 = __half22float2(H2[(size_t)p3.x * 64 + lane]);
                ax = fmaf(v0, g0.x, ax); ay = fmaf(v0, g0.y, ay);
                ax = fmaf(v1, g1.x, ax); ay = fmaf(v1, g1.y, ay);
                ax = fmaf(v2, g2.x, ax); ay = fmaf(v2, g2.y, ay);
                ax = fmaf(v3, g3.x, ax); ay = fmaf(v3, g3.y, ay);
            }
            for (; e < e1; e++) {
                int2 p = ev[e];
                float v = __int_as_float(p.y);
                if constexpr (PREMUL) {
                    v *= dinv[p.x];
                    if (lane == 0) ev[e].y = __float_as_int(v);
                }
                float2 g = __half22float2(H2[(size_t)p.x * 64 + lane]);
                ax = fmaf(v, g.x, ax);
                ay = fmaf(v, g.y, ay);
            }
            ax = fmaxf(ax + bb.x, 0.f);
            ay = fmaxf(ay + bb.y, 0.f);
        }
        ((__half2*)&Xs[lrow * 136])[lane] = __float22half2_rn(make_float2(ax, ay));
    }
    __syncthreads();

    // ---- phase 2: GEMM tile @ Wt ----
    int rg = wv & 3;                       // row group: rows rg*16..+15
    int ch = wv >> 2;                      // column parity: nt = ch, ch+2, ...
    int m  = lane & 15;
    int q  = lane >> 4;

    half8 af[4];
    #pragma unroll
    for (int kt = 0; kt < 4; kt++)
        af[kt] = *(const half8*)&Xs[(rg * 16 + m) * 136 + kt * 32 + q * 8];
    __syncthreads();                       // all af loaded before any C overwrite

    constexpr int NACC = (NT + 1) / 2;
    floatx4 acc[NACC];
    #pragma unroll
    for (int i = 0; i < NACC; i++) { acc[i][0] = 0.f; acc[i][1] = 0.f; acc[i][2] = 0.f; acc[i][3] = 0.f; }

    #pragma unroll
    for (int i = 0; i < NACC; i++) {
        int nt = ch + 2 * i;
        if (nt < NT) {
            const _Float16* wp = Wt + (size_t)(nt * 16 + m) * 128 + q * 8;
            half8 b0 = *(const half8*)(wp);
            half8 b1 = *(const half8*)(wp + 32);
            half8 b2 = *(const half8*)(wp + 64);
            half8 b3 = *(const half8*)(wp + 96);
            acc[i] = __builtin_amdgcn_mfma_f32_16x16x32_f16(af[0], b0, acc[i], 0, 0, 0);
            acc[i] = __builtin_amdgcn_mfma_f32_16x16x32_f16(af[1], b1, acc[i], 0, 0, 0);
            acc[i] = __builtin_amdgcn_mfma_f32_16x16x32_f16(af[2], b2, acc[i], 0, 0, 0);
            acc[i] = __builtin_amdgcn_mfma_f32_16x16x32_f16(af[3], b3, acc[i], 0, 0, 0);
        }
    }

    // C -> LDS (rowgroup rg, column blocks nt of this parity — disjoint addrs)
    #pragma unroll
    for (int i = 0; i < NACC; i++) {
        int nt = ch + 2 * i;
        if (nt < NT) {
            #pragma unroll
            for (int rr = 0; rr < 4; rr++)
                Xs[(rg * 16 + q * 4 + rr) * 136 + nt * 16 + m] = (_Float16)acc[i][rr];
        }
    }
    __syncthreads();                       // columns of a row come from both parities

    // coalesced copy-out
    if constexpr (F_OUT == 128) {
        for (int g = lane; g < 128; g += 64) {
            int rr = g >> 3, c8 = (g & 7) + ch * 8;
            int row = row0 + rg * 16 + rr;
            if (row < N_NODES)
                *(int4*)((__half*)Hout + (size_t)row * 128 + c8 * 8) =
                    *(const int4*)&Xs[(rg * 16 + rr) * 136 + c8 * 8];
        }
    } else {                               // F_OUT = 40: 80 int4 per rowgroup, split by ch
        for (int g = lane + ch * 40; g < 40 + ch * 40; g += 64) {
            int rr = g / 5, seg = g - rr * 5;
            int row = row0 + rg * 16 + rr;
            if (row < N_NODES)
                *(int4*)((__half*)Hout + (size_t)row * 40 + seg * 8) =
                    *(const int4*)&Xs[(rg * 16 + rr) * 136 + seg * 8];
        }
    }
}

// ---------------- Aggregation, 40 half features -> fp32 out with bias ----------------
// Two 32-lane halves each take alternate edges; cross-half reduce via shfl_xor(32).
// ev.y fully premultiplied by the first aggemm.

__global__ __launch_bounds__(256) void agg40_k(const __half* __restrict__ Y,
        const int2* __restrict__ ev, const int* __restrict__ rowptr,
        const float* __restrict__ dinv, const float* __restrict__ bias,
        float* __restrict__ out) {
    int lane = threadIdx.x & 63;
    int node = __builtin_amdgcn_readfirstlane(blockIdx.x * 4 + (threadIdx.x >> 6));
    if (node >= N_NODES) return;
    const __half2* __restrict__ Y2 = (const __half2*)Y;
    int h = lane >> 5;                         // half-wave 0/1
    int l = lane & 31;
    int f = (l < 20) ? l : 0;                  // feature pair index
    float di = dinv[node];
    float dii = di * di;
    float ax = 0.f, ay = 0.f;
    if (h == 0) {
        float2 ys = __half22float2(Y2[(size_t)node * 20 + f]);
        ax = dii * ys.x; ay = dii * ys.y;
    }
    int e0 = rowptr[node], e1 = rowptr[node + 1];
    int e = e0;
    for (; e + 4 <= e1; e += 4) {              // each half-wave: 2 of the 4 edges
        int2 p0 = ev[e + h * 2 + 0];
        int2 p1 = ev[e + h * 2 + 1];
        float2 g0 = __half22float2(Y2[(size_t)p0.x * 20 + f]);
        float2 g1 = __half22float2(Y2[(size_t)p1.x * 20 + f]);
        float v0 = __int_as_float(p0.y);
        float v1 = __int_as_float(p1.y);
        ax = fmaf(v0, g0.x, ax); ay = fmaf(v0, g0.y, ay);
        ax = fmaf(v1, g1.x, ax); ay = fmaf(v1, g1.y, ay);
    }
    for (int ee = e + h; ee < e1; ee += 2) {   // remainder split across halves
        int2 p = ev[ee];
        float v = __int_as_float(p.y);
        float2 g = __half22float2(Y2[(size_t)p.x * 20 + f]);
        ax = fmaf(v, g.x, ax);
        ay = fmaf(v, g.y, ay);
    }
    ax += __shfl_xor(ax, 32);
    ay += __shfl_xor(ay, 32);
    if (lane < 20) {
        float2 b = *(const float2*)&bias[2 * lane];
        float2 o;
        o.x = ax + b.x;
        o.y = ay + b.y;
        *(float2*)&out[(size_t)node * 40 + 2 * lane] = o;
    }
}

// ---------------- launch ----------------

extern "C" void kernel_launch(void* const* d_in, const int* in_sizes, int n_in,
                              void* d_out, int out_size, void* d_ws, size_t ws_size,
                              hipStream_t stream) {
    const float* x  = (const float*)d_in[0];
    const int*   ei = (const int*)d_in[1];
    const int*   src = ei;
    const int*   dst = ei + N_EDGES;
    const float* ew = (const float*)d_in[2];
    const float* W1 = (const float*)d_in[3];
    const float* b1 = (const float*)d_in[4];
    const float* W2 = (const float*)d_in[5];
    const float* b2 = (const float*)d_in[6];
    const float* W3 = (const float*)d_in[7];
    const float* b3 = (const float*)d_in[8];
    float* out = (float*)d_out;

    char* w = (char*)d_ws;
    auto alloc = [&](size_t bytes) {
        char* p = w;
        w += (bytes + 255) & ~(size_t)255;
        return p;
    };
    float*     dinv   = (float*)    alloc((size_t)N_NODES * 4);
    int*       rowptr = (int*)      alloc((size_t)(N_NODES + 1) * 4);
    int*       gh     = (int*)      alloc((size_t)NBLK * NBUCK * 4);
    int*       total  = (int*)      alloc((size_t)NBUCK * 4);
    int2*      bkt    = (int2*)     alloc((size_t)N_EDGES * 8);
    int2*      ev     = (int2*)     alloc((size_t)N_EDGES * 8);
    __half*    hbuf   = (__half*)   alloc((size_t)N_NODES * 128 * 2);
    __half*    abuf   = (__half*)   alloc((size_t)N_NODES * 128 * 2);
    __half*    ybuf   = (__half*)   alloc((size_t)N_NODES * 40 * 2);
    _Float16*  Wt1    = (_Float16*) alloc((size_t)128 * 128 * 2);
    _Float16*  Wt2    = (_Float16*) alloc((size_t)128 * 128 * 2);
    _Float16*  Wt3    = (_Float16*) alloc((size_t)48 * 128 * 2);

    constexpr int GA = (N_NODES + 3) / 4;

    wconv_k<<<152, 256, 0, stream>>>(W1, W2, W3, Wt1, Wt2, Wt3);
    // fused: P1 bucket histogram + gemm1 (x @ W1 -> hbuf half, MFMA)
    gemm_mfma_k<float, 128, 8, true><<<NBLK + GBM, 256, 0, stream>>>(x, Wt1, hbuf, dst, gh);
    scan1_k<<<NBUCK, 256, 0, stream>>>(gh, total);
    bucket_k<<<NBLK, 256, 0, stream>>>(src, dst, ew, gh, total, bkt);
    final_k<<<NBUCK, 256, 0, stream>>>(bkt, total, ev, rowptr, dinv);

    // fused: agg1(+premul writeback)+gemm2 -> abuf ; agg2+gemm3 -> ybuf
    aggemm_k<128, 8, true ><<<GBM, 512, 0, stream>>>(hbuf, ev, rowptr, dinv, b1, Wt2, abuf);
    aggemm_k<40,  3, false><<<GBM, 512, 0, stream>>>(abuf, ev, rowptr, dinv, b2, Wt3, ybuf);
    agg40_k<<<GA, 256, 0, stream>>>(ybuf, ev, rowptr, dinv, b3, out);
}